// Round 6
// baseline (185.212 us; speedup 1.0000x reference)
//
#include <hip/hip_runtime.h>
#include <hip/hip_bf16.h>

typedef __attribute__((ext_vector_type(8))) short short8;
typedef __attribute__((ext_vector_type(4))) short short4v;
typedef __attribute__((ext_vector_type(4))) float float4v;

#define S_DIM 128
#define N_DIM 256
#define CM    256
#define CH    32
#define CZ    128

static __device__ __forceinline__ short f2bf(float v) {
    return __builtin_bit_cast(short, __float2bfloat16(v));
}

// ---------------------------------------------------------------------------
// Fused aux kernel, 384 blocks x 256 thr (unchanged):
//   blocks [0,256):   LayerNorm + dual projection -> a_t/b_t [N*CH][S] bf16.
//   blocks [256,320): wo -> fragment-ordered wo_f.
//   blocks [320,384): ninv[i][j] = 1/(sum_s mask[s,i]mask[s,j] + 1e-3).
// ---------------------------------------------------------------------------
__global__ __launch_bounds__(256) void prep_aux_kernel(
    const float* __restrict__ m, const float* __restrict__ mask,
    const float* __restrict__ lnw, const float* __restrict__ lnb,
    const float* __restrict__ w1, const float* __restrict__ b1,
    const float* __restrict__ w2, const float* __restrict__ b2,
    const float* __restrict__ wo, const float* __restrict__ bo,
    __hip_bfloat16* __restrict__ a_t, __hip_bfloat16* __restrict__ b_t,
    __hip_bfloat16* __restrict__ wo_f, float* __restrict__ ninv)
{
    __shared__ __align__(16) char lds_raw[101376];
    __hip_bfloat16* ln_lds = (__hip_bfloat16*)lds_raw;             // 128 x 264
    __hip_bfloat16* w_lds  = (__hip_bfloat16*)(lds_raw + 67584);   // 64 x 264
    __hip_bfloat16* st_lds = (__hip_bfloat16*)lds_raw;             // 256 x 40 (overlay)

    const int bid = blockIdx.x, t = threadIdx.x;

    if (bid >= 320) {                       // ---- norm ----
        int i0 = (bid - 320) * 4, j = t;
        float a0 = 0.f, a1 = 0.f, a2 = 0.f, a3 = 0.f;
        for (int s = 0; s < S_DIM; ++s) {
            float mj = mask[s * N_DIM + j];
            a0 += mask[s * N_DIM + i0 + 0] * mj;
            a1 += mask[s * N_DIM + i0 + 1] * mj;
            a2 += mask[s * N_DIM + i0 + 2] * mj;
            a3 += mask[s * N_DIM + i0 + 3] * mj;
        }
        ninv[(i0 + 0) * N_DIM + j] = 1.0f / (a0 + 1e-3f);
        ninv[(i0 + 1) * N_DIM + j] = 1.0f / (a1 + 1e-3f);
        ninv[(i0 + 2) * N_DIM + j] = 1.0f / (a2 + 1e-3f);
        ninv[(i0 + 3) * N_DIM + j] = 1.0f / (a3 + 1e-3f);
        return;
    }
    if (bid >= 256) {                       // ---- wot ----
        int fidx = (bid - 256) * 256 + t;
        int l  = fidx & 63;
        int d  = (fidx >> 6) & 31;
        int zt = fidx >> 11;
        int z  = zt * 16 + (l & 15);
        int cb = (l >> 4) * 8;
        short8 frag;
        #pragma unroll
        for (int j = 0; j < 8; ++j)
            frag[j] = f2bf(wo[(size_t)((cb + j) * 32 + d) * CZ + z]);
        *(short8*)&wo_f[(size_t)fidx * 8] = frag;
        return;
    }

    // ---- prep: 4 n x 32 s per block ----
    const int lane = t & 63, wv = t >> 6;
    const int q = lane >> 4, c16 = lane & 15;
    const int n0 = (bid & 63) * 4, s0 = (bid >> 6) * 32;

    #pragma unroll 4
    for (int i = 0; i < 64; ++i) {
        int e = i * 256 + t;
        int k = e >> 6, c = e & 63;
        float v = (c < CH) ? w1[k * CH + c] : w2[k * CH + (c - CH)];
        w_lds[c * 264 + k] = __float2bfloat16(v);
    }

    float4 lw = ((const float4*)lnw)[lane];
    float4 lb = ((const float4*)lnb)[lane];

    #pragma unroll 2
    for (int it = 0; it < 32; ++it) {
        int rl = wv * 32 + it;
        int r  = (s0 + (rl >> 2)) * N_DIM + n0 + (rl & 3);
        float4 mv = ((const float4*)(m + (size_t)r * CM))[lane];
        float s1 = mv.x + mv.y + mv.z + mv.w;
        float s2 = mv.x*mv.x + mv.y*mv.y + mv.z*mv.z + mv.w*mv.w;
        #pragma unroll
        for (int o = 32; o > 0; o >>= 1) {
            s1 += __shfl_xor(s1, o, 64);
            s2 += __shfl_xor(s2, o, 64);
        }
        float mu  = s1 * (1.0f / 256.0f);
        float var = s2 * (1.0f / 256.0f) - mu * mu;
        float rs  = rsqrtf(var + 1e-5f);
        int base = rl * 264 + lane * 4;
        ln_lds[base + 0] = __float2bfloat16((mv.x - mu) * rs * lw.x + lb.x);
        ln_lds[base + 1] = __float2bfloat16((mv.y - mu) * rs * lw.y + lb.y);
        ln_lds[base + 2] = __float2bfloat16((mv.z - mu) * rs * lw.z + lb.z);
        ln_lds[base + 3] = __float2bfloat16((mv.w - mu) * rs * lw.w + lb.w);
    }
    __syncthreads();

    float4v acc[2][4];
    #pragma unroll
    for (int rt = 0; rt < 2; ++rt)
        #pragma unroll
        for (int ct = 0; ct < 4; ++ct)
            acc[rt][ct] = (float4v){0.f, 0.f, 0.f, 0.f};
    #pragma unroll
    for (int ks = 0; ks < 8; ++ks) {
        int k0 = ks * 32 + q * 8;
        short8 af0 = *(const short8*)&ln_lds[(wv * 32      + c16) * 264 + k0];
        short8 af1 = *(const short8*)&ln_lds[(wv * 32 + 16 + c16) * 264 + k0];
        #pragma unroll
        for (int ct = 0; ct < 4; ++ct) {
            short8 wb = *(const short8*)&w_lds[(ct * 16 + c16) * 264 + k0];
            acc[0][ct] = __builtin_amdgcn_mfma_f32_16x16x32_bf16(af0, wb, acc[0][ct], 0, 0, 0);
            acc[1][ct] = __builtin_amdgcn_mfma_f32_16x16x32_bf16(af1, wb, acc[1][ct], 0, 0, 0);
        }
    }
    __syncthreads();

    #pragma unroll
    for (int rt = 0; rt < 2; ++rt) {
        int sl = wv * 8 + rt * 4 + q;
        #pragma unroll
        for (int ct = 0; ct < 4; ++ct) {
            int cc = ct * 16 + c16;
            float bias = (cc < CH) ? b1[cc] : b2[cc - CH];
            #pragma unroll
            for (int rr = 0; rr < 4; ++rr) {
                int r = (s0 + sl) * N_DIM + n0 + rr;
                float val = (acc[rt][ct][rr] + bias) * mask[r];
                st_lds[(rr * 64 + cc) * 40 + sl] = __float2bfloat16(val);
            }
        }
    }
    __syncthreads();

    {
        int nl = t >> 6, cc = t & 63;
        int colg = (n0 + nl) * CH + (cc < CH ? cc : cc - CH);
        __hip_bfloat16* dst = (cc < CH ? a_t : b_t) + (size_t)colg * S_DIM + s0;
        #pragma unroll
        for (int v = 0; v < 4; ++v)
            *(short8*)(dst + v * 8) = *(const short8*)&st_lds[t * 40 + v * 8];
    }
}

// ---------------------------------------------------------------------------
// Main kernel v3: 2 j-tiles per block. A AND B fragments register-resident
// (rows shared by only 2 waves -> LDS staging buys nothing). Outer phase has
// ZERO barriers; single __syncthreads() before the epilogue. LDS = P1+P2 only
// (fragment order): P_tau at tau*16512, 33024 shorts = 64.5 KB.
// ---------------------------------------------------------------------------
__global__ __launch_bounds__(256, 2) void main_kernel(
    const __hip_bfloat16* __restrict__ a_t, const __hip_bfloat16* __restrict__ b_t,
    const __hip_bfloat16* __restrict__ wo_f, const float* __restrict__ bo,
    const float* __restrict__ ninv, float* __restrict__ out)
{
    __shared__ __align__(16) short lds[33024];

    const int t = threadIdx.x, l = t & 63, wv = t >> 6;
    const int q = l >> 4, c16 = l & 15;
    const int bi = blockIdx.x, bj0 = blockIdx.y * 2;
    const int wr = wv >> 1, wc = wv & 1;
    const size_t Ibase = (size_t)bi * 128;

    // A fragments -> registers, once. af[sk][ti], sk = K quarter.
    short8 af[4][4];
    #pragma unroll
    for (int sk = 0; sk < 4; ++sk) {
        int koff = sk * 32 + q * 8;
        #pragma unroll
        for (int ti = 0; ti < 4; ++ti) {
            int row = wr * 64 + ti * 16 + c16;
            af[sk][ti] = *(const short8*)&a_t[(Ibase + row) * S_DIM + koff];
        }
    }

    #pragma unroll
    for (int tau = 0; tau < 2; ++tau) {
        const size_t Jbase = (size_t)(bj0 + tau) * 128;

        // B fragments -> registers for this tile
        short8 bf[4][4];
        #pragma unroll
        for (int sk = 0; sk < 4; ++sk) {
            int koff = sk * 32 + q * 8;
            #pragma unroll
            for (int tj = 0; tj < 4; ++tj) {
                int row = wc * 64 + tj * 16 + c16;
                bf[sk][tj] = *(const short8*)&b_t[(Jbase + row) * S_DIM + koff];
            }
        }

        float4v acc[4][4];
        #pragma unroll
        for (int ti = 0; ti < 4; ++ti)
            #pragma unroll
            for (int tj = 0; tj < 4; ++tj)
                acc[ti][tj] = (float4v){0.f, 0.f, 0.f, 0.f};

        #pragma unroll
        for (int sk = 0; sk < 4; ++sk)
            #pragma unroll
            for (int ti = 0; ti < 4; ++ti)
                #pragma unroll
                for (int tj = 0; tj < 4; ++tj)
                    acc[ti][tj] = __builtin_amdgcn_mfma_f32_16x16x32_bf16(
                        af[sk][ti], bf[sk][tj], acc[ti][tj], 0, 0, 0);

        // scatter acc -> P_tau (fragment order), no barrier needed
        const int pb = tau * 16512;
        #pragma unroll
        for (int ti = 0; ti < 4; ++ti)
            #pragma unroll
            for (int tj = 0; tj < 4; ++tj) {
                int d  = ((tj & 1) * 16) + c16;
                int c0 = ((ti & 1) * 16) + q * 4;
                int p  = (wr * 2 + (ti >> 1)) * 4 + wc * 2 + (tj >> 1);
                short4v pk;
                #pragma unroll
                for (int rr = 0; rr < 4; ++rr)
                    pk[rr] = f2bf(acc[ti][tj][rr]);
                *(short4v*)&lds[pb + d * 516 + (c0 >> 3) * 128 + p * 8 + (c0 & 7)] = pk;
            }
    }
    __syncthreads();   // the ONLY barrier

    // Epilogue: [2 tiles x 16 pairs x 1024] @ wo_f -> 2 x [16 x 128].
    // Wave wv owns z-tiles 2wv, 2wv+1; wo_f read once for BOTH tiles.
    float4v oacc[2][2];
    #pragma unroll
    for (int a = 0; a < 2; ++a)
        #pragma unroll
        for (int b = 0; b < 2; ++b)
            oacc[a][b] = (float4v){0.f, 0.f, 0.f, 0.f};
    const __hip_bfloat16* wbase0 = wo_f + (size_t)(wv * 2    ) * 32 * 512;
    const __hip_bfloat16* wbase1 = wo_f + (size_t)(wv * 2 + 1) * 32 * 512;
    #pragma unroll 4
    for (int d = 0; d < 32; ++d) {
        union { short8 v8; short4v v4[2]; } p1, p2;
        p1.v4[0] = *(const short4v*)&lds[        d * 516 + l * 8];
        p1.v4[1] = *(const short4v*)&lds[        d * 516 + l * 8 + 4];
        p2.v4[0] = *(const short4v*)&lds[16512 + d * 516 + l * 8];
        p2.v4[1] = *(const short4v*)&lds[16512 + d * 516 + l * 8 + 4];
        short8 wf0 = *(const short8*)&wbase0[(size_t)(d * 64 + l) * 8];
        short8 wf1 = *(const short8*)&wbase1[(size_t)(d * 64 + l) * 8];
        oacc[0][0] = __builtin_amdgcn_mfma_f32_16x16x32_bf16(p1.v8, wf0, oacc[0][0], 0, 0, 0);
        oacc[0][1] = __builtin_amdgcn_mfma_f32_16x16x32_bf16(p1.v8, wf1, oacc[0][1], 0, 0, 0);
        oacc[1][0] = __builtin_amdgcn_mfma_f32_16x16x32_bf16(p2.v8, wf0, oacc[1][0], 0, 0, 0);
        oacc[1][1] = __builtin_amdgcn_mfma_f32_16x16x32_bf16(p2.v8, wf1, oacc[1][1], 0, 0, 0);
    }

    // D: row = pair = q*4+rr -> (i_loc = q, j_loc = rr); col = z offset = c16
    const int gi = bi * 4 + q;
    #pragma unroll
    for (int tau = 0; tau < 2; ++tau) {
        const int bj = bj0 + tau;
        float nvv[4];
        #pragma unroll
        for (int rr = 0; rr < 4; ++rr)
            nvv[rr] = ninv[gi * N_DIM + bj * 4 + rr];
        #pragma unroll
        for (int tile = 0; tile < 2; ++tile) {
            int z = wv * 32 + tile * 16 + c16;
            float bz = bo[z];
            float4v oa = oacc[tau][tile];
            #pragma unroll
            for (int rr = 0; rr < 4; ++rr) {
                int gj = bj * 4 + rr;
                out[((size_t)gi * N_DIM + gj) * CZ + z] = (oa[rr] + bz) * nvv[rr];
            }
        }
    }
}

extern "C" void kernel_launch(void* const* d_in, const int* in_sizes, int n_in,
                              void* d_out, int out_size, void* d_ws, size_t ws_size,
                              hipStream_t stream) {
    const float* m    = (const float*)d_in[0];
    const float* mask = (const float*)d_in[1];
    const float* lnw  = (const float*)d_in[2];
    const float* lnb  = (const float*)d_in[3];
    const float* w1   = (const float*)d_in[4];
    const float* b1   = (const float*)d_in[5];
    const float* w2   = (const float*)d_in[6];
    const float* b2   = (const float*)d_in[7];
    const float* wo   = (const float*)d_in[8];
    const float* bo   = (const float*)d_in[9];
    float* out = (float*)d_out;

    char* ws = (char*)d_ws;
    __hip_bfloat16* a_t  = (__hip_bfloat16*)ws;                          // 2 MB
    __hip_bfloat16* b_t  = (__hip_bfloat16*)(ws + (2u << 20));           // 2 MB
    __hip_bfloat16* wo_f = (__hip_bfloat16*)(ws + (4u << 20));           // 256 KB
    float*          ninv = (float*)(ws + (4u << 20) + (256u << 10));     // 256 KB

    prep_aux_kernel<<<384, 256, 0, stream>>>(m, mask, lnw, lnb, w1, b1, w2, b2,
                                             wo, bo, a_t, b_t, wo_f, ninv);
    main_kernel<<<dim3(64, 32), 256, 0, stream>>>(a_t, b_t, wo_f, bo, ninv, out);
}

// Round 7
// 169.346 us; speedup vs baseline: 1.0937x; 1.0937x over previous
//
#include <hip/hip_runtime.h>
#include <hip/hip_bf16.h>

typedef __attribute__((ext_vector_type(8))) short short8;
typedef __attribute__((ext_vector_type(4))) short short4v;
typedef __attribute__((ext_vector_type(4))) float float4v;

#define S_DIM 128
#define N_DIM 256
#define CM    256
#define CH    32
#define CZ    128

static __device__ __forceinline__ short f2bf(float v) {
    return __builtin_bit_cast(short, __float2bfloat16(v));
}

// ---------------------------------------------------------------------------
// Fused aux kernel, 384 blocks x 256 thr (unchanged):
//   blocks [0,256):   LayerNorm + dual projection -> a_t/b_t [N*CH][S] bf16.
//   blocks [256,320): wo -> fragment-ordered wo_f.
//   blocks [320,384): ninv[i][j] = 1/(sum_s mask[s,i]mask[s,j] + 1e-3).
// ---------------------------------------------------------------------------
__global__ __launch_bounds__(256) void prep_aux_kernel(
    const float* __restrict__ m, const float* __restrict__ mask,
    const float* __restrict__ lnw, const float* __restrict__ lnb,
    const float* __restrict__ w1, const float* __restrict__ b1,
    const float* __restrict__ w2, const float* __restrict__ b2,
    const float* __restrict__ wo, const float* __restrict__ bo,
    __hip_bfloat16* __restrict__ a_t, __hip_bfloat16* __restrict__ b_t,
    __hip_bfloat16* __restrict__ wo_f, float* __restrict__ ninv)
{
    __shared__ __align__(16) char lds_raw[101376];
    __hip_bfloat16* ln_lds = (__hip_bfloat16*)lds_raw;             // 128 x 264
    __hip_bfloat16* w_lds  = (__hip_bfloat16*)(lds_raw + 67584);   // 64 x 264
    __hip_bfloat16* st_lds = (__hip_bfloat16*)lds_raw;             // 256 x 40 (overlay)

    const int bid = blockIdx.x, t = threadIdx.x;

    if (bid >= 320) {                       // ---- norm ----
        int i0 = (bid - 320) * 4, j = t;
        float a0 = 0.f, a1 = 0.f, a2 = 0.f, a3 = 0.f;
        for (int s = 0; s < S_DIM; ++s) {
            float mj = mask[s * N_DIM + j];
            a0 += mask[s * N_DIM + i0 + 0] * mj;
            a1 += mask[s * N_DIM + i0 + 1] * mj;
            a2 += mask[s * N_DIM + i0 + 2] * mj;
            a3 += mask[s * N_DIM + i0 + 3] * mj;
        }
        ninv[(i0 + 0) * N_DIM + j] = 1.0f / (a0 + 1e-3f);
        ninv[(i0 + 1) * N_DIM + j] = 1.0f / (a1 + 1e-3f);
        ninv[(i0 + 2) * N_DIM + j] = 1.0f / (a2 + 1e-3f);
        ninv[(i0 + 3) * N_DIM + j] = 1.0f / (a3 + 1e-3f);
        return;
    }
    if (bid >= 256) {                       // ---- wot ----
        int fidx = (bid - 256) * 256 + t;
        int l  = fidx & 63;
        int d  = (fidx >> 6) & 31;
        int zt = fidx >> 11;
        int z  = zt * 16 + (l & 15);
        int cb = (l >> 4) * 8;
        short8 frag;
        #pragma unroll
        for (int j = 0; j < 8; ++j)
            frag[j] = f2bf(wo[(size_t)((cb + j) * 32 + d) * CZ + z]);
        *(short8*)&wo_f[(size_t)fidx * 8] = frag;
        return;
    }

    // ---- prep: 4 n x 32 s per block ----
    const int lane = t & 63, wv = t >> 6;
    const int q = lane >> 4, c16 = lane & 15;
    const int n0 = (bid & 63) * 4, s0 = (bid >> 6) * 32;

    #pragma unroll 4
    for (int i = 0; i < 64; ++i) {
        int e = i * 256 + t;
        int k = e >> 6, c = e & 63;
        float v = (c < CH) ? w1[k * CH + c] : w2[k * CH + (c - CH)];
        w_lds[c * 264 + k] = __float2bfloat16(v);
    }

    float4 lw = ((const float4*)lnw)[lane];
    float4 lb = ((const float4*)lnb)[lane];

    #pragma unroll 2
    for (int it = 0; it < 32; ++it) {
        int rl = wv * 32 + it;
        int r  = (s0 + (rl >> 2)) * N_DIM + n0 + (rl & 3);
        float4 mv = ((const float4*)(m + (size_t)r * CM))[lane];
        float s1 = mv.x + mv.y + mv.z + mv.w;
        float s2 = mv.x*mv.x + mv.y*mv.y + mv.z*mv.z + mv.w*mv.w;
        #pragma unroll
        for (int o = 32; o > 0; o >>= 1) {
            s1 += __shfl_xor(s1, o, 64);
            s2 += __shfl_xor(s2, o, 64);
        }
        float mu  = s1 * (1.0f / 256.0f);
        float var = s2 * (1.0f / 256.0f) - mu * mu;
        float rs  = rsqrtf(var + 1e-5f);
        int base = rl * 264 + lane * 4;
        ln_lds[base + 0] = __float2bfloat16((mv.x - mu) * rs * lw.x + lb.x);
        ln_lds[base + 1] = __float2bfloat16((mv.y - mu) * rs * lw.y + lb.y);
        ln_lds[base + 2] = __float2bfloat16((mv.z - mu) * rs * lw.z + lb.z);
        ln_lds[base + 3] = __float2bfloat16((mv.w - mu) * rs * lw.w + lb.w);
    }
    __syncthreads();

    float4v acc[2][4];
    #pragma unroll
    for (int rt = 0; rt < 2; ++rt)
        #pragma unroll
        for (int ct = 0; ct < 4; ++ct)
            acc[rt][ct] = (float4v){0.f, 0.f, 0.f, 0.f};
    #pragma unroll
    for (int ks = 0; ks < 8; ++ks) {
        int k0 = ks * 32 + q * 8;
        short8 af0 = *(const short8*)&ln_lds[(wv * 32      + c16) * 264 + k0];
        short8 af1 = *(const short8*)&ln_lds[(wv * 32 + 16 + c16) * 264 + k0];
        #pragma unroll
        for (int ct = 0; ct < 4; ++ct) {
            short8 wb = *(const short8*)&w_lds[(ct * 16 + c16) * 264 + k0];
            acc[0][ct] = __builtin_amdgcn_mfma_f32_16x16x32_bf16(af0, wb, acc[0][ct], 0, 0, 0);
            acc[1][ct] = __builtin_amdgcn_mfma_f32_16x16x32_bf16(af1, wb, acc[1][ct], 0, 0, 0);
        }
    }
    __syncthreads();

    #pragma unroll
    for (int rt = 0; rt < 2; ++rt) {
        int sl = wv * 8 + rt * 4 + q;
        #pragma unroll
        for (int ct = 0; ct < 4; ++ct) {
            int cc = ct * 16 + c16;
            float bias = (cc < CH) ? b1[cc] : b2[cc - CH];
            #pragma unroll
            for (int rr = 0; rr < 4; ++rr) {
                int r = (s0 + sl) * N_DIM + n0 + rr;
                float val = (acc[rt][ct][rr] + bias) * mask[r];
                st_lds[(rr * 64 + cc) * 40 + sl] = __float2bfloat16(val);
            }
        }
    }
    __syncthreads();

    {
        int nl = t >> 6, cc = t & 63;
        int colg = (n0 + nl) * CH + (cc < CH ? cc : cc - CH);
        __hip_bfloat16* dst = (cc < CH ? a_t : b_t) + (size_t)colg * S_DIM + s0;
        #pragma unroll
        for (int v = 0; v < 4; ++v)
            *(short8*)(dst + v * 8) = *(const short8*)&st_lds[t * 40 + v * 8];
    }
}

// ---------------------------------------------------------------------------
// Main kernel v4: 512 threads (8 waves) per block covering 128 I x 256 J
// (2 j-tiles). Same per-block traffic/LDS as v2 but 2x waves/CU (16 vs 8).
// A frags registers; B staged in LDS per 64-K stage; P frag-ordered, stride
// 520 (16B-aligned -> single ds_read_b128 in epilogue).
// LDS: B stage [0,8192); P_t1 [0,16640) overlays B; P_t0 [16640,33280).
// ---------------------------------------------------------------------------
__global__ __launch_bounds__(512, 4) void main_kernel(
    const __hip_bfloat16* __restrict__ a_t, const __hip_bfloat16* __restrict__ b_t,
    const __hip_bfloat16* __restrict__ wo_f, const float* __restrict__ bo,
    const float* __restrict__ ninv, float* __restrict__ out)
{
    __shared__ __align__(16) short lds[33280];

    const int t = threadIdx.x, l = t & 63, wv = t >> 6;   // wv 0..7
    const int q = l >> 4, c16 = l & 15;
    const int bi = blockIdx.x, bj0 = blockIdx.y * 2;
    const int wr = wv & 3, wc = wv >> 2;                  // 4 i-subtiles x 2 j-halves
    const size_t Ibase = (size_t)bi * 128;

    // A fragments -> registers. af[sk][ti]: rows wr*32 + ti*16 + c16.
    short8 af[4][2];
    #pragma unroll
    for (int sk = 0; sk < 4; ++sk) {
        int koff = sk * 32 + q * 8;
        #pragma unroll
        for (int ti = 0; ti < 2; ++ti) {
            int row = wr * 32 + ti * 16 + c16;
            af[sk][ti] = *(const short8*)&a_t[(Ibase + row) * S_DIM + koff];
        }
    }

    #pragma unroll
    for (int tau = 0; tau < 2; ++tau) {
        const size_t Jbase = (size_t)(bj0 + tau) * 128;
        float4v acc[2][4];
        #pragma unroll
        for (int ti = 0; ti < 2; ++ti)
            #pragma unroll
            for (int tj = 0; tj < 4; ++tj)
                acc[ti][tj] = (float4v){0.f, 0.f, 0.f, 0.f};

        #pragma unroll
        for (int st = 0; st < 2; ++st) {
            // stage B (128 rows x 64 k) -> LDS [0,8192), frag order
            #pragma unroll
            for (int i = 0; i < 2; ++i) {
                int f  = i * 8 + wv;
                int h  = f >> 3, ti = (f >> 1) & 3, kk = f & 1;
                int row  = h * 64 + ti * 16 + c16;
                int koff = st * 64 + kk * 32 + q * 8;
                *(short8*)&lds[f * 512 + l * 8] =
                    *(const short8*)&b_t[(Jbase + row) * S_DIM + koff];
            }
            __syncthreads();
            #pragma unroll
            for (int kk = 0; kk < 2; ++kk) {
                short8 bf[4];
                #pragma unroll
                for (int tj = 0; tj < 4; ++tj)
                    bf[tj] = *(const short8*)&lds[((wc * 4 + tj) * 2 + kk) * 512 + l * 8];
                #pragma unroll
                for (int ti = 0; ti < 2; ++ti)
                    #pragma unroll
                    for (int tj = 0; tj < 4; ++tj)
                        acc[ti][tj] = __builtin_amdgcn_mfma_f32_16x16x32_bf16(
                            af[st * 2 + kk][ti], bf[tj], acc[ti][tj], 0, 0, 0);
            }
            __syncthreads();   // all B reads done before region reuse
        }

        // scatter acc -> P_tau (t0 high, t1 low/overlay). Value (pair p,
        // c=Il&31, d=Jl&31) -> frag d, offset (c>>3)*128 + p*8 + (c&7).
        const int pb = tau ? 0 : 16640;
        #pragma unroll
        for (int ti = 0; ti < 2; ++ti)
            #pragma unroll
            for (int tj = 0; tj < 4; ++tj) {
                int d  = ((tj & 1) * 16) + c16;
                int c0 = ti * 16 + q * 4;
                int p  = wr * 4 + wc * 2 + (tj >> 1);
                short4v pk;
                #pragma unroll
                for (int rr = 0; rr < 4; ++rr)
                    pk[rr] = f2bf(acc[ti][tj][rr]);
                *(short4v*)&lds[pb + d * 520 + (c0 >> 3) * 128 + p * 8 + (c0 & 7)] = pk;
            }
    }
    __syncthreads();

    // Epilogue: [2 tiles x 16 pairs x 1024] @ wo_f. Wave wv owns z-tile wv.
    float4v oacc[2];
    oacc[0] = (float4v){0.f, 0.f, 0.f, 0.f};
    oacc[1] = (float4v){0.f, 0.f, 0.f, 0.f};
    const __hip_bfloat16* wbase = wo_f + (size_t)wv * 32 * 512;
    #pragma unroll 4
    for (int d = 0; d < 32; ++d) {
        short8 p0 = *(const short8*)&lds[16640 + d * 520 + l * 8];
        short8 p1 = *(const short8*)&lds[        d * 520 + l * 8];
        short8 wf = *(const short8*)&wbase[(size_t)(d * 512 + l * 8)];
        oacc[0] = __builtin_amdgcn_mfma_f32_16x16x32_bf16(p0, wf, oacc[0], 0, 0, 0);
        oacc[1] = __builtin_amdgcn_mfma_f32_16x16x32_bf16(p1, wf, oacc[1], 0, 0, 0);
    }

    // D: row = pair = q*4+rr; col = z offset = c16. z = wv*16 + c16.
    const int gi = bi * 4 + q;
    const int z  = wv * 16 + c16;
    const float bz = bo[z];
    #pragma unroll
    for (int tau = 0; tau < 2; ++tau) {
        const int bj = bj0 + tau;
        #pragma unroll
        for (int rr = 0; rr < 4; ++rr) {
            int gj = bj * 4 + rr;
            float nv = ninv[gi * N_DIM + gj];
            out[((size_t)gi * N_DIM + gj) * CZ + z] = (oacc[tau][rr] + bz) * nv;
        }
    }
}

extern "C" void kernel_launch(void* const* d_in, const int* in_sizes, int n_in,
                              void* d_out, int out_size, void* d_ws, size_t ws_size,
                              hipStream_t stream) {
    const float* m    = (const float*)d_in[0];
    const float* mask = (const float*)d_in[1];
    const float* lnw  = (const float*)d_in[2];
    const float* lnb  = (const float*)d_in[3];
    const float* w1   = (const float*)d_in[4];
    const float* b1   = (const float*)d_in[5];
    const float* w2   = (const float*)d_in[6];
    const float* b2   = (const float*)d_in[7];
    const float* wo   = (const float*)d_in[8];
    const float* bo   = (const float*)d_in[9];
    float* out = (float*)d_out;

    char* ws = (char*)d_ws;
    __hip_bfloat16* a_t  = (__hip_bfloat16*)ws;                          // 2 MB
    __hip_bfloat16* b_t  = (__hip_bfloat16*)(ws + (2u << 20));           // 2 MB
    __hip_bfloat16* wo_f = (__hip_bfloat16*)(ws + (4u << 20));           // 256 KB
    float*          ninv = (float*)(ws + (4u << 20) + (256u << 10));     // 256 KB

    prep_aux_kernel<<<384, 256, 0, stream>>>(m, mask, lnw, lnb, w1, b1, w2, b2,
                                             wo, bo, a_t, b_t, wo_f, ninv);
    main_kernel<<<dim3(64, 32), 512, 0, stream>>>(a_t, b_t, wo_f, bo, ninv, out);
}

// Round 8
// 147.073 us; speedup vs baseline: 1.2593x; 1.1514x over previous
//
#include <hip/hip_runtime.h>
#include <hip/hip_bf16.h>

typedef __attribute__((ext_vector_type(8))) short short8;
typedef __attribute__((ext_vector_type(4))) short short4v;
typedef __attribute__((ext_vector_type(4))) float float4v;

#define S_DIM 128
#define N_DIM 256
#define CM    256
#define CH    32
#define CZ    128

static __device__ __forceinline__ short f2bf(float v) {
    return __builtin_bit_cast(short, __float2bfloat16(v));
}

// ---------------------------------------------------------------------------
// a_f/b_f global layout = MFMA fragment order:
//   element (row, k)  [row = n*32+c (a) or n*32+d (b), k = s]
//   -> a_f[(x*4 + sk)*512 + q*128 + (row&15)*8 + (k&7)]
//      x = row>>4, sk = k>>5, q = (k>>3)&3   (lane l = q*16 + (row&15))
// Every main-kernel load of these arrays is base + l*8 (lane-linear 1KB).
// ---------------------------------------------------------------------------

// ---------------------------------------------------------------------------
// Fused aux kernel, 640 blocks x 256 thr:
//   blocks [0,512):   LN + dual projection. Block = 2 n x 32 s x 64 cols.
//                     LDS 76KB -> 2 blocks/CU. Frag-order coalesced stores.
//   blocks [512,576): wo -> fragment-ordered wo_f.
//   blocks [576,640): ninv[i][j] = 1/(sum_s mask[s,i]mask[s,j] + 1e-3).
// ---------------------------------------------------------------------------
__global__ __launch_bounds__(256) void prep_aux_kernel(
    const float* __restrict__ m, const float* __restrict__ mask,
    const float* __restrict__ lnw, const float* __restrict__ lnb,
    const float* __restrict__ w1, const float* __restrict__ b1,
    const float* __restrict__ w2, const float* __restrict__ b2,
    const float* __restrict__ wo, const float* __restrict__ bo,
    __hip_bfloat16* __restrict__ a_f, __hip_bfloat16* __restrict__ b_f,
    __hip_bfloat16* __restrict__ wo_f, float* __restrict__ ninv)
{
    __shared__ __align__(16) char lds_raw[77824];
    __hip_bfloat16* ln_lds = (__hip_bfloat16*)lds_raw;             // 64 x 264
    __hip_bfloat16* w_lds  = (__hip_bfloat16*)(lds_raw + 33792);   // 64 x 264
    __hip_bfloat16* st_lds = (__hip_bfloat16*)(lds_raw + 67584);   // 128 x 40

    const int bid = blockIdx.x, t = threadIdx.x;

    if (bid >= 576) {                       // ---- norm ----
        int i0 = (bid - 576) * 4, j = t;
        float a0 = 0.f, a1 = 0.f, a2 = 0.f, a3 = 0.f;
        for (int s = 0; s < S_DIM; ++s) {
            float mj = mask[s * N_DIM + j];
            a0 += mask[s * N_DIM + i0 + 0] * mj;
            a1 += mask[s * N_DIM + i0 + 1] * mj;
            a2 += mask[s * N_DIM + i0 + 2] * mj;
            a3 += mask[s * N_DIM + i0 + 3] * mj;
        }
        ninv[(i0 + 0) * N_DIM + j] = 1.0f / (a0 + 1e-3f);
        ninv[(i0 + 1) * N_DIM + j] = 1.0f / (a1 + 1e-3f);
        ninv[(i0 + 2) * N_DIM + j] = 1.0f / (a2 + 1e-3f);
        ninv[(i0 + 3) * N_DIM + j] = 1.0f / (a3 + 1e-3f);
        return;
    }
    if (bid >= 512) {                       // ---- wot ----
        int fidx = (bid - 512) * 256 + t;   // 16384 lane-slots
        int l  = fidx & 63;
        int d  = (fidx >> 6) & 31;
        int zt = fidx >> 11;
        int z  = zt * 16 + (l & 15);
        int cb = (l >> 4) * 8;
        short8 frag;
        #pragma unroll
        for (int j = 0; j < 8; ++j)
            frag[j] = f2bf(wo[(size_t)((cb + j) * 32 + d) * CZ + z]);
        *(short8*)&wo_f[(size_t)fidx * 8] = frag;
        return;
    }

    // ---- prep: 2 n x 32 s per block ----
    const int lane = t & 63, wv = t >> 6;
    const int q = lane >> 4, c16 = lane & 15;
    const int n0 = (bid & 127) * 2, s0 = (bid >> 7) * 32, sk = bid >> 7;

    // stage w transposed: w_t[c][k] = w{1,2}[k][c]
    #pragma unroll 4
    for (int i = 0; i < 64; ++i) {
        int e = i * 256 + t;
        int k = e >> 6, c = e & 63;
        float v = (c < CH) ? w1[k * CH + c] : w2[k * CH + (c - CH)];
        w_lds[c * 264 + k] = __float2bfloat16(v);
    }

    float4 lw = ((const float4*)lnw)[lane];
    float4 lb = ((const float4*)lnb)[lane];

    // LN: wave wv owns rows rl = wv*16 + it  (rl = sl*2 + nl)
    #pragma unroll 2
    for (int it = 0; it < 16; ++it) {
        int rl = wv * 16 + it;
        int r  = (s0 + (rl >> 1)) * N_DIM + n0 + (rl & 1);
        float4 mv = ((const float4*)(m + (size_t)r * CM))[lane];
        float s1 = mv.x + mv.y + mv.z + mv.w;
        float s2 = mv.x*mv.x + mv.y*mv.y + mv.z*mv.z + mv.w*mv.w;
        #pragma unroll
        for (int o = 32; o > 0; o >>= 1) {
            s1 += __shfl_xor(s1, o, 64);
            s2 += __shfl_xor(s2, o, 64);
        }
        float mu  = s1 * (1.0f / 256.0f);
        float var = s2 * (1.0f / 256.0f) - mu * mu;
        float rs  = rsqrtf(var + 1e-5f);
        int base = rl * 264 + lane * 4;
        ln_lds[base + 0] = __float2bfloat16((mv.x - mu) * rs * lw.x + lb.x);
        ln_lds[base + 1] = __float2bfloat16((mv.y - mu) * rs * lw.y + lb.y);
        ln_lds[base + 2] = __float2bfloat16((mv.z - mu) * rs * lw.z + lb.z);
        ln_lds[base + 3] = __float2bfloat16((mv.w - mu) * rs * lw.w + lb.w);
    }
    __syncthreads();   // w_lds ready (ln rows are wave-local)

    // MFMA: wave = 16 rows x 64 cols, K=256
    float4v acc[4];
    #pragma unroll
    for (int ct = 0; ct < 4; ++ct) acc[ct] = (float4v){0.f, 0.f, 0.f, 0.f};
    #pragma unroll
    for (int ks = 0; ks < 8; ++ks) {
        int k0 = ks * 32 + q * 8;
        short8 af = *(const short8*)&ln_lds[(wv * 16 + c16) * 264 + k0];
        #pragma unroll
        for (int ct = 0; ct < 4; ++ct) {
            short8 wb = *(const short8*)&w_lds[(ct * 16 + c16) * 264 + k0];
            acc[ct] = __builtin_amdgcn_mfma_f32_16x16x32_bf16(af, wb, acc[ct], 0, 0, 0);
        }
    }

    // scatter: C/D row = wv*16 + q*4 + rr -> sl = rl>>1, nl = rl&1
    #pragma unroll
    for (int ct = 0; ct < 4; ++ct) {
        int cc = ct * 16 + c16;                 // 0..63 (a: <32, b: >=32)
        float bias = (cc < CH) ? b1[cc] : b2[cc - CH];
        #pragma unroll
        for (int rr = 0; rr < 4; ++rr) {
            int rl = wv * 16 + q * 4 + rr;
            int r  = (s0 + (rl >> 1)) * N_DIM + n0 + (rl & 1);
            float val = (acc[ct][rr] + bias) * mask[r];
            st_lds[((rl & 1) * 64 + cc) * 40 + (rl >> 1)] = __float2bfloat16(val);
        }
    }
    __syncthreads();

    // frag-order coalesced store: 512 slots (8 frags x 64 lanes), 2/thread
    #pragma unroll
    for (int i = 0; i < 2; ++i) {
        int slot = i * 256 + t;
        int f8 = slot >> 6, l = slot & 63;
        int fl = f8 & 3, nl = fl >> 1, cch = fl & 1;
        int lq = l >> 4, lc16 = l & 15;
        int col = nl * 64 + (f8 >= 4 ? 32 : 0) + cch * 16 + lc16;
        short8 v = *(const short8*)&st_lds[col * 40 + lq * 8];
        __hip_bfloat16* base = (f8 >= 4) ? b_f : a_f;
        *(short8*)&base[(size_t)((n0 * 2 + fl) * 4 + sk) * 512 + l * 8] = v;
    }
}

// ---------------------------------------------------------------------------
// Main kernel v5: 512 thr (8 waves), 128 I x 256 J per block. All global
// loads lane-linear (a_f/b_f/wo_f frag order). A frags in regs; B staged in
// LDS; epilogue wo_f prefetched 8-deep ping-pong in regs.
// LDS: B stage [0,8192); P_t1 [0,16640) overlays B; P_t0 [16640,33280).
// ---------------------------------------------------------------------------
__global__ __launch_bounds__(512, 4) void main_kernel(
    const __hip_bfloat16* __restrict__ a_f, const __hip_bfloat16* __restrict__ b_f,
    const __hip_bfloat16* __restrict__ wo_f, const float* __restrict__ bo,
    const float* __restrict__ ninv, float* __restrict__ out)
{
    __shared__ __align__(16) short lds[33280];

    const int t = threadIdx.x, l = t & 63, wv = t >> 6;   // wv 0..7
    const int q = l >> 4, c16 = l & 15;
    const int bi = blockIdx.x, bj0 = blockIdx.y * 2;
    const int wr = wv & 3, wc = wv >> 2;
    const size_t Ix = (size_t)bi * 8;

    // A fragments -> registers (lane-linear loads)
    short8 af[4][2];
    #pragma unroll
    for (int sk = 0; sk < 4; ++sk)
        #pragma unroll
        for (int ti = 0; ti < 2; ++ti)
            af[sk][ti] = *(const short8*)&a_f[((Ix + wr * 2 + ti) * 4 + sk) * 512 + l * 8];

    #pragma unroll
    for (int tau = 0; tau < 2; ++tau) {
        const size_t Jx = (size_t)(bj0 + tau) * 8;
        float4v acc[2][4];
        #pragma unroll
        for (int ti = 0; ti < 2; ++ti)
            #pragma unroll
            for (int tj = 0; tj < 4; ++tj)
                acc[ti][tj] = (float4v){0.f, 0.f, 0.f, 0.f};

        #pragma unroll
        for (int st = 0; st < 2; ++st) {
            // stage B -> LDS [0,8192), frag id flds = x_local*2 + kk
            #pragma unroll
            for (int i = 0; i < 2; ++i) {
                int f  = i * 8 + wv;
                int xl = f >> 1, kk = f & 1;
                *(short8*)&lds[f * 512 + l * 8] =
                    *(const short8*)&b_f[((Jx + xl) * 4 + st * 2 + kk) * 512 + l * 8];
            }
            __syncthreads();
            #pragma unroll
            for (int kk = 0; kk < 2; ++kk) {
                short8 bf[4];
                #pragma unroll
                for (int tj = 0; tj < 4; ++tj)
                    bf[tj] = *(const short8*)&lds[((wc * 4 + tj) * 2 + kk) * 512 + l * 8];
                #pragma unroll
                for (int ti = 0; ti < 2; ++ti)
                    #pragma unroll
                    for (int tj = 0; tj < 4; ++tj)
                        acc[ti][tj] = __builtin_amdgcn_mfma_f32_16x16x32_bf16(
                            af[st * 2 + kk][ti], bf[tj], acc[ti][tj], 0, 0, 0);
            }
            __syncthreads();
        }

        // scatter acc -> P_tau. (pair p, c=Il&31, d=Jl&31) ->
        // frag d, offset (c>>3)*128 + p*8 + (c&7). stride 520.
        const int pb = tau ? 0 : 16640;
        #pragma unroll
        for (int ti = 0; ti < 2; ++ti)
            #pragma unroll
            for (int tj = 0; tj < 4; ++tj) {
                int d  = ((tj & 1) * 16) + c16;
                int c0 = ti * 16 + q * 4;
                int p  = wr * 4 + wc * 2 + (tj >> 1);
                short4v pk;
                #pragma unroll
                for (int rr = 0; rr < 4; ++rr)
                    pk[rr] = f2bf(acc[ti][tj][rr]);
                *(short4v*)&lds[pb + d * 520 + (c0 >> 3) * 128 + p * 8 + (c0 & 7)] = pk;
            }
    }
    __syncthreads();

    // Epilogue: wave wv owns z-tile wv; wo_f prefetched 8-deep ping-pong.
    float4v oacc[2];
    oacc[0] = (float4v){0.f, 0.f, 0.f, 0.f};
    oacc[1] = (float4v){0.f, 0.f, 0.f, 0.f};
    const __hip_bfloat16* wbase = wo_f + (size_t)wv * 32 * 512;
    short8 wA[4], wB[4];
    #pragma unroll
    for (int dd = 0; dd < 4; ++dd) {
        wA[dd] = *(const short8*)&wbase[(dd    ) * 512 + l * 8];
        wB[dd] = *(const short8*)&wbase[(dd + 4) * 512 + l * 8];
    }
    #pragma unroll
    for (int c = 0; c < 8; ++c) {
        #pragma unroll
        for (int dd = 0; dd < 4; ++dd) {
            int d = c * 4 + dd;
            short8 wf = (c & 1) ? wB[dd] : wA[dd];
            short8 p0 = *(const short8*)&lds[16640 + d * 520 + l * 8];
            short8 p1 = *(const short8*)&lds[        d * 520 + l * 8];
            if (c < 6) {
                short8 wn = *(const short8*)&wbase[(d + 8) * 512 + l * 8];
                if (c & 1) wB[dd] = wn; else wA[dd] = wn;
            }
            oacc[0] = __builtin_amdgcn_mfma_f32_16x16x32_bf16(p0, wf, oacc[0], 0, 0, 0);
            oacc[1] = __builtin_amdgcn_mfma_f32_16x16x32_bf16(p1, wf, oacc[1], 0, 0, 0);
        }
    }

    // D: row = pair = q*4+rr; col = z offset = c16. z = wv*16 + c16.
    const int gi = bi * 4 + q;
    const int z  = wv * 16 + c16;
    const float bz = bo[z];
    #pragma unroll
    for (int tau = 0; tau < 2; ++tau) {
        const int bj = bj0 + tau;
        #pragma unroll
        for (int rr = 0; rr < 4; ++rr) {
            int gj = bj * 4 + rr;
            float nv = ninv[gi * N_DIM + gj];
            out[((size_t)gi * N_DIM + gj) * CZ + z] = (oacc[tau][rr] + bz) * nv;
        }
    }
}

extern "C" void kernel_launch(void* const* d_in, const int* in_sizes, int n_in,
                              void* d_out, int out_size, void* d_ws, size_t ws_size,
                              hipStream_t stream) {
    const float* m    = (const float*)d_in[0];
    const float* mask = (const float*)d_in[1];
    const float* lnw  = (const float*)d_in[2];
    const float* lnb  = (const float*)d_in[3];
    const float* w1   = (const float*)d_in[4];
    const float* b1   = (const float*)d_in[5];
    const float* w2   = (const float*)d_in[6];
    const float* b2   = (const float*)d_in[7];
    const float* wo   = (const float*)d_in[8];
    const float* bo   = (const float*)d_in[9];
    float* out = (float*)d_out;

    char* ws = (char*)d_ws;
    __hip_bfloat16* a_f  = (__hip_bfloat16*)ws;                          // 2 MB
    __hip_bfloat16* b_f  = (__hip_bfloat16*)(ws + (2u << 20));           // 2 MB
    __hip_bfloat16* wo_f = (__hip_bfloat16*)(ws + (4u << 20));           // 256 KB
    float*          ninv = (float*)(ws + (4u << 20) + (256u << 10));     // 256 KB

    prep_aux_kernel<<<640, 256, 0, stream>>>(m, mask, lnw, lnb, w1, b1, w2, b2,
                                             wo, bo, a_f, b_f, wo_f, ninv);
    main_kernel<<<dim3(64, 32), 512, 0, stream>>>(a_f, b_f, wo_f, bo, ninv, out);
}